// Round 6
// baseline (865.574 us; speedup 1.0000x reference)
//
#include <hip/hip_runtime.h>
#include <stdint.h>

typedef _Float16 f16;
typedef _Float16 f16x4 __attribute__((ext_vector_type(4)));
typedef _Float16 f16x8 __attribute__((ext_vector_type(8)));
typedef float    f32x4 __attribute__((ext_vector_type(4)));

#define LO_SCALE 2048.0f

__device__ __forceinline__ void llds16(const void* g, void* l) {
    __builtin_amdgcn_global_load_lds(
        (const __attribute__((address_space(1))) void*)g,
        (__attribute__((address_space(3))) void*)l, 16, 0, 0);
}

__device__ __forceinline__ unsigned long long pack_key(float s, int j) {
    unsigned u = __float_as_uint(s);
    u = (u & 0x80000000u) ? ~u : (u | 0x80000000u);
    return ((unsigned long long)u << 32) | (unsigned)(~(unsigned)j);
}

// ---------------- convert emb -> Bh/Bl fp16 + rinv/2048 ----------------
__global__ void convert_emb_kernel(const float* __restrict__ emb,
                                   f16* __restrict__ bh, f16* __restrict__ bl,
                                   float* __restrict__ rinv, int V, int E) {
    int row  = blockIdx.x * (blockDim.x >> 6) + (threadIdx.x >> 6);
    int lane = threadIdx.x & 63;
    if (row >= V) return;
    const float4* p = (const float4*)(emb + (size_t)row * E);
    int n4 = E >> 2;
    float ss = 0.f;
    for (int i = lane; i < n4; i += 64) {
        float4 v = p[i];
        ss = fmaf(v.x, v.x, ss); ss = fmaf(v.y, v.y, ss);
        ss = fmaf(v.z, v.z, ss); ss = fmaf(v.w, v.w, ss);
    }
    #pragma unroll
    for (int o = 32; o > 0; o >>= 1) ss += __shfl_down(ss, o, 64);
    if (lane == 0) rinv[row] = 1.0f / (sqrtf(ss) * LO_SCALE);

    for (int i = lane; i < n4; i += 64) {
        float4 v = p[i];
        f16x4 h, l;
        h.x = (f16)v.x; l.x = (f16)((v.x - (float)h.x) * LO_SCALE);
        h.y = (f16)v.y; l.y = (f16)((v.y - (float)h.y) * LO_SCALE);
        h.z = (f16)v.z; l.z = (f16)((v.z - (float)h.z) * LO_SCALE);
        h.w = (f16)v.w; l.w = (f16)((v.w - (float)h.w) * LO_SCALE);
        *(f16x4*)&bh[(size_t)row * E + i * 4] = h;
        *(f16x4*)&bl[(size_t)row * E + i * 4] = l;
    }
}

// ---------------- convert batch -> Ahs(=2048*Ah)/Ah/Al ----------------
__global__ void convert_batch_kernel(const float* __restrict__ batch,
                                     f16* __restrict__ ahs, f16* __restrict__ ah,
                                     f16* __restrict__ al, int M, int E) {
    int row  = blockIdx.x * (blockDim.x >> 6) + (threadIdx.x >> 6);
    int lane = threadIdx.x & 63;
    if (row >= M) return;
    const float4* p = (const float4*)(batch + (size_t)row * E);
    int n4 = E >> 2;
    for (int i = lane; i < n4; i += 64) {
        float4 v = p[i];
        f16x4 h, hs, l;
        float t;
        h.x = (f16)v.x; t = (float)h.x * LO_SCALE; t = fminf(fmaxf(t, -65000.f), 65000.f);
        hs.x = (f16)t;  l.x = (f16)((v.x - (float)h.x) * LO_SCALE);
        h.y = (f16)v.y; t = (float)h.y * LO_SCALE; t = fminf(fmaxf(t, -65000.f), 65000.f);
        hs.y = (f16)t;  l.y = (f16)((v.y - (float)h.y) * LO_SCALE);
        h.z = (f16)v.z; t = (float)h.z * LO_SCALE; t = fminf(fmaxf(t, -65000.f), 65000.f);
        hs.z = (f16)t;  l.z = (f16)((v.z - (float)h.z) * LO_SCALE);
        h.w = (f16)v.w; t = (float)h.w * LO_SCALE; t = fminf(fmaxf(t, -65000.f), 65000.f);
        hs.w = (f16)t;  l.w = (f16)((v.w - (float)h.w) * LO_SCALE);
        *(f16x4*)&ahs[(size_t)row * E + i * 4] = hs;
        *(f16x4*)&ah [(size_t)row * E + i * 4] = h;
        *(f16x4*)&al [(size_t)row * E + i * 4] = l;
    }
}

// ---------------- init packed keys ----------------
__global__ void init_keys_kernel(unsigned long long* __restrict__ keys, int M) {
    int i = blockIdx.x * blockDim.x + threadIdx.x;
    if (i < M) keys[i] = 0ULL;
}

// ---------------- 4-phase/K-tile pipelined MFMA GEMM + fused argmax ----------------
// Effective GEMM: C = [2048*Ah | Ah | Al] x [Bh | Bl | Bh]^T, K = 3*512 = 1536.
// LDS addressed ENTIRELY in 16-byte f16x8 units so every fragment read is a
// provably-aligned ds_read_b128 (rounds 3-5 used char*+offset casts -> compiler
// could not prove alignment -> split loads -> LDS-issue-bound at ~31% MfmaUtil).
#define BM 256
#define BN 256
#define BK 64            // halfs per K-tile
#define EH 512           // E in halfs (hardcoded fast path)
#define NT 24            // K-tiles total (1536/64)
#define BUF_U 4096       // one buffer in 16B units (64 KB)
#define AH0_U 0
#define AH1_U 1024
#define BH0_U 2048
#define BH1_U 3072

#define WAIT4  asm volatile("s_waitcnt vmcnt(4)" ::: "memory")
#define WAIT0  asm volatile("s_waitcnt vmcnt(0)" ::: "memory")
#define LGK0   asm volatile("s_waitcnt lgkmcnt(0)" ::: "memory")

__global__ __launch_bounds__(512, 2) void nn_mfma_pipe(
    const f16* __restrict__ Ahs, const f16* __restrict__ Ah, const f16* __restrict__ Al,
    const f16* __restrict__ Bh, const f16* __restrict__ Bl,
    const float* __restrict__ rinv, unsigned long long* __restrict__ keys,
    int M, int V)
{
    extern __shared__ f16x8 smem[];   // typed, 16B elements -> alignment known

    const int tid  = threadIdx.x;
    const int lane = tid & 63;
    const int w    = tid >> 6;      // wave 0..7
    const int wm   = w >> 2;        // 0..1
    const int wn   = w & 3;         // 0..3
    const int fr   = lane & 15;
    const int kg   = lane >> 4;     // 0..3

    // bijective XCD swizzle; mb fastest so consecutive blocks share B panel
    const int nwg = gridDim.x;
    const int bid = blockIdx.x;
    const int swz = ((nwg & 7) == 0) ? ((bid & 7) * (nwg >> 3) + (bid >> 3)) : bid;
    const int mblocks = M / BM;
    const int mb = swz % mblocks;
    const int nb = swz / mblocks;
    const int row0 = mb * BM;
    const int col0 = nb * BN;

    // ---- staging addressing (per wave: 2 gload_lds per half-tile) ----
    const int r8 = lane >> 3;             // 0..7
    const int sl = lane & 7;              // 16B slot
    const int xs = (sl ^ r8) * 8;         // pre-swizzled source col (halfs)
    int aoffL[2], boffL[2][2];
    #pragma unroll
    for (int i = 0; i < 2; ++i) {
        int ar = row0 + w * 16 + i * 8 + r8;          // A rows in half0; half1 adds 128
        aoffL[i] = ar * EH + xs;
        #pragma unroll
        for (int h = 0; h < 2; ++h) {
            int c = col0 + h * 128 + w * 16 + i * 8 + r8;
            if (c > V - 1) c = V - 1;
            boffL[h][i] = c * EH + xs;
        }
    }
    const int ldsdU0 = w * 128;           // (w*16 rows) * 8 units/row
    const int ldsdU1 = w * 128 + 64;      // +8 rows

    auto stage = [&](int bufi, int hsel, int tt) {
        const int seg  = tt >> 3;                    // 0,1,2
        const int koff = (tt & 7) * BK;              // halfs
        f16x8* base = smem + bufi * BUF_U
                      + (hsel == 0 ? AH0_U : hsel == 1 ? AH1_U
                                           : hsel == 2 ? BH0_U : BH1_U);
        if (hsel < 2) {       // A half hsel: seg0 Ahs, seg1 Ah, seg2 Al
            const f16* src = (seg == 0) ? Ahs : (seg == 1) ? Ah : Al;
            const f16* g = src + (size_t)hsel * 128 * EH + koff;
            llds16(g + aoffL[0], (void*)(base + ldsdU0));
            llds16(g + aoffL[1], (void*)(base + ldsdU1));
        } else {              // B half (hsel-2): seg0 Bh, seg1 Bl, seg2 Bh
            const int h = hsel - 2;
            const f16* src = (seg == 1) ? Bl : Bh;
            llds16(src + boffL[h][0] + koff, (void*)(base + ldsdU0));
            llds16(src + boffL[h][1] + koff, (void*)(base + ldsdU1));
        }
    };

    // ---- fragment read offsets in 16B units (swizzled read) ----
    int aRB[4], bCB[2], cx[2];
    #pragma unroll
    for (int mm = 0; mm < 4; ++mm) aRB[mm] = (wm * 64 + mm * 16 + fr) * 8;
    #pragma unroll
    for (int nn2 = 0; nn2 < 2; ++nn2) bCB[nn2] = (wn * 32 + nn2 * 16 + fr) * 8;
    #pragma unroll
    for (int kk = 0; kk < 2; ++kk) cx[kk] = (kk * 4 + kg) ^ (fr & 7);

    f32x4 acc[8][4];
    #pragma unroll
    for (int m = 0; m < 8; ++m)
        #pragma unroll
        for (int n = 0; n < 4; ++n) acc[m][n] = (f32x4){0.f, 0.f, 0.f, 0.f};

    // ---- prologue: tile0 fully + A0(1), B1(1) in flight; verify tile0 ----
    stage(0, 0, 0); stage(0, 2, 0); stage(0, 1, 0); stage(0, 3, 0);
    stage(1, 0, 1); stage(1, 3, 1);
    WAIT4;
    __builtin_amdgcn_s_barrier();

    #define MFMA_Q(MH, NH, BFREG)                                                   \
        __builtin_amdgcn_s_setprio(1);                                              \
        _Pragma("unroll")                                                           \
        for (int mm = 0; mm < 4; ++mm) {                                            \
            _Pragma("unroll")                                                       \
            for (int nn2 = 0; nn2 < 2; ++nn2) {                                     \
                _Pragma("unroll")                                                   \
                for (int kk = 0; kk < 2; ++kk)                                      \
                    acc[(MH)*4+mm][(NH)*2+nn2] =                                    \
                        __builtin_amdgcn_mfma_f32_16x16x32_f16(                     \
                            af[mm][kk], BFREG[nn2][kk],                             \
                            acc[(MH)*4+mm][(NH)*2+nn2], 0, 0, 0);                   \
            }                                                                       \
        }                                                                           \
        __builtin_amdgcn_s_setprio(0);

    #pragma unroll 1
    for (int t = 0; t < NT; ++t) {
        const int cbU = (t & 1) * BUF_U;  // current buffer base (units)
        const int nb1 = (t + 1) & 1;      // buffer of tile t+1
        const int cbi = t & 1;            // buffer of tile t (== tile t+2)
        f16x8 af[4][2], bf0[2][2], bf1[2][2];

        // ---- p0 (Q00): read af<-A0, bf0<-B0; stage A1(t+1) ----
        #pragma unroll
        for (int mm = 0; mm < 4; ++mm)
            #pragma unroll
            for (int kk = 0; kk < 2; ++kk)
                af[mm][kk] = smem[cbU + AH0_U + aRB[mm] + cx[kk]];
        #pragma unroll
        for (int nn2 = 0; nn2 < 2; ++nn2)
            #pragma unroll
            for (int kk = 0; kk < 2; ++kk)
                bf0[nn2][kk] = smem[cbU + BH0_U + bCB[nn2] + cx[kk]];
        if (t + 1 < NT) stage(nb1, 1, t + 1);
        __builtin_amdgcn_s_barrier();
        LGK0;
        MFMA_Q(0, 0, bf0)
        __builtin_amdgcn_s_barrier();

        // ---- p1 (Q01): read bf1<-B1; stage B0(t+1) ----
        #pragma unroll
        for (int nn2 = 0; nn2 < 2; ++nn2)
            #pragma unroll
            for (int kk = 0; kk < 2; ++kk)
                bf1[nn2][kk] = smem[cbU + BH1_U + bCB[nn2] + cx[kk]];
        if (t + 1 < NT) stage(nb1, 2, t + 1);
        __builtin_amdgcn_s_barrier();
        LGK0;
        MFMA_Q(0, 1, bf1)
        __builtin_amdgcn_s_barrier();

        // ---- p2 (Q11): read af<-A1; stage A0(t+2) ----
        #pragma unroll
        for (int mm = 0; mm < 4; ++mm)
            #pragma unroll
            for (int kk = 0; kk < 2; ++kk)
                af[mm][kk] = smem[cbU + AH1_U + aRB[mm] + cx[kk]];
        if (t + 2 < NT) stage(cbi, 0, t + 2);
        __builtin_amdgcn_s_barrier();
        LGK0;
        MFMA_Q(1, 1, bf1)
        __builtin_amdgcn_s_barrier();

        // ---- p3 (Q10): no reads; stage B1(t+2); single counted vm-wait ----
        if (t + 2 < NT) stage(cbi, 3, t + 2);
        __builtin_amdgcn_s_barrier();
        MFMA_Q(1, 0, bf0)
        if (t + 2 < NT)      { WAIT4; }
        else if (t + 1 < NT) { WAIT0; }
        __builtin_amdgcn_s_barrier();
    }
    #undef MFMA_Q

    // ---- epilogue: s = acc * (rinv/2048); fused argmax ----
    float ri[4];
    #pragma unroll
    for (int nn = 0; nn < 4; ++nn) {
        int j = col0 + (nn >> 1) * 128 + wn * 32 + (nn & 1) * 16 + fr;
        ri[nn] = (j < V) ? rinv[j] : 0.f;
    }
    #pragma unroll
    for (int m = 0; m < 8; ++m) {
        #pragma unroll
        for (int r = 0; r < 4; ++r) {
            unsigned long long best = 0ULL;
            #pragma unroll
            for (int nn = 0; nn < 4; ++nn) {
                int j = col0 + (nn >> 1) * 128 + wn * 32 + (nn & 1) * 16 + fr;
                if (j < V) {
                    unsigned long long key = pack_key(acc[m][nn][r] * ri[nn], j);
                    if (key > best) best = key;
                }
            }
            #pragma unroll
            for (int o = 8; o > 0; o >>= 1) {
                unsigned long long other = __shfl_xor(best, o, 64);
                if (other > best) best = other;
            }
            if (fr == 0 && best != 0ULL) {
                int row = row0 + (m >> 2) * 128 + wm * 64 + (m & 3) * 16 + kg * 4 + r;
                atomicMax(&keys[row], best);
            }
        }
    }
}

// ---------------- extract indices ----------------
__global__ void extract_kernel(const unsigned long long* __restrict__ keys,
                               int* __restrict__ out, int M) {
    int i = blockIdx.x * blockDim.x + threadIdx.x;
    if (i < M) out[i] = (int)(~(unsigned)(keys[i] & 0xFFFFFFFFULL));
}

// ================= fallback fp32 path (round-0, validated) =================
__global__ void inv_norms_kernel(const float* __restrict__ emb,
                                 float* __restrict__ r, int V, int E) {
    int row  = blockIdx.x * (blockDim.x >> 6) + (threadIdx.x >> 6);
    int lane = threadIdx.x & 63;
    if (row >= V) return;
    const float4* p = reinterpret_cast<const float4*>(emb + (size_t)row * E);
    float ss = 0.f;
    int n4 = E >> 2;
    for (int i = lane; i < n4; i += 64) {
        float4 v = p[i];
        ss = fmaf(v.x, v.x, ss); ss = fmaf(v.y, v.y, ss);
        ss = fmaf(v.z, v.z, ss); ss = fmaf(v.w, v.w, ss);
    }
    #pragma unroll
    for (int o = 32; o > 0; o >>= 1) ss += __shfl_down(ss, o, 64);
    if (lane == 0) r[row] = 1.0f / sqrtf(ss);
}

#define FBM 128
#define FBN 128
#define FBK 32
#define LDSPAD 4

__global__ __launch_bounds__(256) void nn_gemm_argmax(
    const float* __restrict__ batch, const float* __restrict__ emb,
    const float* __restrict__ rinv, unsigned long long* __restrict__ keys,
    int M, int V, int E)
{
    __shared__ float As[FBK][FBM + LDSPAD];
    __shared__ float Bs[FBK][FBN + LDSPAD];
    const int tid = threadIdx.x;
    const int tx  = tid & 15;
    const int ty  = tid >> 4;
    const int row0 = blockIdx.y * FBM;
    const int col0 = blockIdx.x * FBN;
    float acc[8][8];
    #pragma unroll
    for (int i = 0; i < 8; ++i)
        #pragma unroll
        for (int j = 0; j < 8; ++j) acc[i][j] = 0.f;
    const int steps = E / FBK;
    for (int ks = 0; ks < steps; ++ks) {
        const int k0 = ks * FBK;
        #pragma unroll
        for (int it = 0; it < 4; ++it) {
            int idx = it * 256 + tid;
            int rr = idx >> 3, cc = idx & 7;
            float4 v = *reinterpret_cast<const float4*>(
                &batch[(size_t)(row0 + rr) * E + k0 + cc * 4]);
            As[cc*4+0][rr] = v.x; As[cc*4+1][rr] = v.y;
            As[cc*4+2][rr] = v.z; As[cc*4+3][rr] = v.w;
        }
        #pragma unroll
        for (int it = 0; it < 4; ++it) {
            int idx = it * 256 + tid;
            int rr = idx >> 3, cc = idx & 7;
            int j = col0 + rr;
            float4 v = make_float4(0.f,0.f,0.f,0.f);
            if (j < V)
                v = *reinterpret_cast<const float4*>(&emb[(size_t)j * E + k0 + cc * 4]);
            Bs[cc*4+0][rr] = v.x; Bs[cc*4+1][rr] = v.y;
            Bs[cc*4+2][rr] = v.z; Bs[cc*4+3][rr] = v.w;
        }
        __syncthreads();
        #pragma unroll
        for (int k = 0; k < FBK; ++k) {
            float4 a0 = *reinterpret_cast<const float4*>(&As[k][ty*8]);
            float4 a1 = *reinterpret_cast<const float4*>(&As[k][ty*8+4]);
            float4 b0 = *reinterpret_cast<const float4*>(&Bs[k][tx*8]);
            float4 b1 = *reinterpret_cast<const float4*>(&Bs[k][tx*8+4]);
            float a[8] = {a0.x,a0.y,a0.z,a0.w,a1.x,a1.y,a1.z,a1.w};
            float b[8] = {b0.x,b0.y,b0.z,b0.w,b1.x,b1.y,b1.z,b1.w};
            #pragma unroll
            for (int i = 0; i < 8; ++i)
                #pragma unroll
                for (int jj = 0; jj < 8; ++jj)
                    acc[i][jj] = fmaf(a[i], b[jj], acc[i][jj]);
        }
        __syncthreads();
    }
    #pragma unroll
    for (int i = 0; i < 8; ++i) {
        const int q = row0 + ty * 8 + i;
        unsigned long long best = 0ULL;
        #pragma unroll
        for (int jj = 0; jj < 8; ++jj) {
            int j = col0 + tx * 8 + jj;
            if (j < V) {
                unsigned long long key = pack_key(acc[i][jj] * rinv[j], j);
                if (key > best) best = key;
            }
        }
        #pragma unroll
        for (int o = 8; o > 0; o >>= 1) {
            unsigned long long other = __shfl_xor(best, o, 64);
            if (other > best) best = other;
        }
        if (tx == 0 && best != 0ULL) atomicMax(&keys[q], best);
    }
}

// ================= launch =================
extern "C" void kernel_launch(void* const* d_in, const int* in_sizes, int n_in,
                              void* d_out, int out_size, void* d_ws, size_t ws_size,
                              hipStream_t stream) {
    const float* batch = (const float*)d_in[0];  // [B,S,E] f32
    const float* emb   = (const float*)d_in[1];  // [V,E]   f32
    int* out = (int*)d_out;

    const int M = out_size;                 // 4096
    const int E = in_sizes[0] / M;          // 512
    const int V = in_sizes[1] / E;          // 50000

    auto al256 = [](size_t x) { return (x + 255) & ~(size_t)255; };
    size_t o_rinv = 0;
    size_t o_keys = al256(o_rinv + (size_t)V * 4);
    size_t o_Ahs  = al256(o_keys + (size_t)M * 8);
    size_t o_Ah   = al256(o_Ahs + (size_t)M * E * 2);
    size_t o_Al   = al256(o_Ah  + (size_t)M * E * 2);
    size_t o_Bh   = al256(o_Al  + (size_t)M * E * 2);
    size_t o_Bl   = al256(o_Bh  + (size_t)V * E * 2);
    size_t need   = al256(o_Bl  + (size_t)V * E * 2);

    unsigned long long* keys = (unsigned long long*)((char*)d_ws + o_keys);
    float* rinv = (float*)((char*)d_ws + o_rinv);

    if (ws_size >= need && E == EH && (M % BM) == 0) {
        f16* Ahs = (f16*)((char*)d_ws + o_Ahs);
        f16* Ah  = (f16*)((char*)d_ws + o_Ah);
        f16* Al  = (f16*)((char*)d_ws + o_Al);
        f16* Bh  = (f16*)((char*)d_ws + o_Bh);
        f16* Bl  = (f16*)((char*)d_ws + o_Bl);

        convert_emb_kernel<<<(V + 3) / 4, 256, 0, stream>>>(emb, Bh, Bl, rinv, V, E);
        convert_batch_kernel<<<(M + 3) / 4, 256, 0, stream>>>(batch, Ahs, Ah, Al, M, E);
        init_keys_kernel<<<(M + 255) / 256, 256, 0, stream>>>(keys, M);

        hipFuncSetAttribute((const void*)nn_mfma_pipe,
                            hipFuncAttributeMaxDynamicSharedMemorySize,
                            2 * BUF_U * 16);

        int nblocks = (M / BM) * ((V + BN - 1) / BN);   // 16 * 196 = 3136
        nn_mfma_pipe<<<nblocks, 512, 2 * BUF_U * 16, stream>>>(Ahs, Ah, Al, Bh, Bl,
                                                               rinv, keys, M, V);

        extract_kernel<<<(M + 255) / 256, 256, 0, stream>>>(keys, out, M);
    } else {
        inv_norms_kernel<<<(V + 3) / 4, 256, 0, stream>>>(emb, rinv, V, E);
        init_keys_kernel<<<(M + 255) / 256, 256, 0, stream>>>(keys, M);
        dim3 grid((V + FBN - 1) / FBN, M / FBM);
        nn_gemm_argmax<<<grid, 256, 0, stream>>>(batch, emb, rinv, keys, M, V, E);
        extract_kernel<<<(M + 255) / 256, 256, 0, stream>>>(keys, out, M);
    }
}

// Round 7
// 470.398 us; speedup vs baseline: 1.8401x; 1.8401x over previous
//
#include <hip/hip_runtime.h>
#include <stdint.h>

typedef _Float16 f16;
typedef _Float16 f16x4 __attribute__((ext_vector_type(4)));
typedef _Float16 f16x8 __attribute__((ext_vector_type(8)));
typedef float    f32x4 __attribute__((ext_vector_type(4)));

__device__ __forceinline__ void llds16(const void* g, void* l) {
    __builtin_amdgcn_global_load_lds(
        (const __attribute__((address_space(1))) void*)g,
        (__attribute__((address_space(3))) void*)l, 16, 0, 0);
}

__device__ __forceinline__ unsigned long long pack_key(float s, int j) {
    unsigned u = __float_as_uint(s);
    u = (u & 0x80000000u) ? ~u : (u | 0x80000000u);
    return ((unsigned long long)u << 32) | (unsigned)(~(unsigned)j);
}

// ---------------- convert emb -> Bh fp16 + plain rinv ----------------
__global__ void convert_emb_kernel(const float* __restrict__ emb,
                                   f16* __restrict__ bh,
                                   float* __restrict__ rinv, int V, int E) {
    int row  = blockIdx.x * (blockDim.x >> 6) + (threadIdx.x >> 6);
    int lane = threadIdx.x & 63;
    if (row >= V) return;
    const float4* p = (const float4*)(emb + (size_t)row * E);
    int n4 = E >> 2;
    float ss = 0.f;
    for (int i = lane; i < n4; i += 64) {
        float4 v = p[i];
        ss = fmaf(v.x, v.x, ss); ss = fmaf(v.y, v.y, ss);
        ss = fmaf(v.z, v.z, ss); ss = fmaf(v.w, v.w, ss);
    }
    #pragma unroll
    for (int o = 32; o > 0; o >>= 1) ss += __shfl_down(ss, o, 64);
    if (lane == 0) rinv[row] = 1.0f / sqrtf(ss);

    for (int i = lane; i < n4; i += 64) {
        float4 v = p[i];
        f16x4 h;
        h.x = (f16)v.x; h.y = (f16)v.y; h.z = (f16)v.z; h.w = (f16)v.w;
        *(f16x4*)&bh[(size_t)row * E + i * 4] = h;
    }
}

// ---------------- convert batch -> Ah fp16 ----------------
__global__ void convert_batch_kernel(const float* __restrict__ batch,
                                     f16* __restrict__ ah, int M, int E) {
    int row  = blockIdx.x * (blockDim.x >> 6) + (threadIdx.x >> 6);
    int lane = threadIdx.x & 63;
    if (row >= M) return;
    const float4* p = (const float4*)(batch + (size_t)row * E);
    int n4 = E >> 2;
    for (int i = lane; i < n4; i += 64) {
        float4 v = p[i];
        f16x4 h;
        h.x = (f16)v.x; h.y = (f16)v.y; h.z = (f16)v.z; h.w = (f16)v.w;
        *(f16x4*)&ah[(size_t)row * E + i * 4] = h;
    }
}

// ---------------- init group-max array ----------------
__global__ void init_bmax_kernel(unsigned* __restrict__ bmax, int n) {
    int i = blockIdx.x * blockDim.x + threadIdx.x;
    for (; i < n; i += gridDim.x * blockDim.x) bmax[i] = 0u;  // ordered(-inf)
}

// ---------------- pass 1: hi*hi MFMA GEMM + per-(row,64col-group) max ----------------
// Structure = round-2's validated kernel minus the lo arrays.
#define BM 128
#define BN 128
#define BKH 64   // K halfs per step

__global__ __launch_bounds__(256, 4) void nn_hh_kernel(
    const f16* __restrict__ Ah, const f16* __restrict__ Bh,
    const float* __restrict__ rinvP, unsigned* __restrict__ bmax,
    int M, int V, int E, int NG)
{
    __shared__ f16 sAh[BM * BKH], sBh[BM * BKH];

    const int tid  = threadIdx.x;
    const int lane = tid & 63;
    const int w    = tid >> 6;      // wave 0..3
    const int wr   = w >> 1;        // wave row 0..1
    const int wc   = w & 1;         // wave col 0..1
    const int fr   = lane & 15;
    const int kg   = lane >> 4;     // 0..3

    const int row0 = blockIdx.x * BM;   // M block
    const int col0 = blockIdx.y * BN;   // N (V) block

    // staging: lane -> (row within 8-row group, 16B slot); pre-swizzled source
    const int srow  = lane >> 3;
    const int sslot = lane & 7;
    const int xslot = sslot ^ srow;
    int aoff[4], boff[4], ldof[4];
    #pragma unroll
    for (int it = 0; it < 4; ++it) {
        int rl = w * 32 + it * 8 + srow;
        aoff[it] = (row0 + rl) * E + xslot * 8;
        int bj = col0 + rl; if (bj > V - 1) bj = V - 1;
        boff[it] = bj * E + xslot * 8;
        ldof[it] = (w * 32 + it * 8) * BKH;
    }

    f32x4 acc[4][4];
    #pragma unroll
    for (int m = 0; m < 4; ++m)
        #pragma unroll
        for (int n = 0; n < 4; ++n) acc[m][n] = (f32x4){0.f, 0.f, 0.f, 0.f};

    const int steps = E / BKH;
    for (int ks = 0; ks < steps; ++ks) {
        const int kadv = ks * BKH;
        #pragma unroll
        for (int it = 0; it < 4; ++it) {
            llds16(Ah + aoff[it] + kadv, sAh + ldof[it]);
            llds16(Bh + boff[it] + kadv, sBh + ldof[it]);
        }
        __syncthreads();

        #pragma unroll
        for (int ksub = 0; ksub < 2; ++ksub) {
            f16x8 ah[4], bh[4];
            #pragma unroll
            for (int m = 0; m < 4; ++m) {
                int row = wr * 64 + m * 16 + fr;
                int off = row * BKH + (((ksub * 4 + kg) ^ (fr & 7)) << 3);
                ah[m] = *(const f16x8*)&sAh[off];
            }
            #pragma unroll
            for (int n = 0; n < 4; ++n) {
                int col = wc * 64 + n * 16 + fr;
                int off = col * BKH + (((ksub * 4 + kg) ^ (fr & 7)) << 3);
                bh[n] = *(const f16x8*)&sBh[off];
            }
            #pragma unroll
            for (int m = 0; m < 4; ++m)
                #pragma unroll
                for (int n = 0; n < 4; ++n)
                    acc[m][n] = __builtin_amdgcn_mfma_f32_16x16x32_f16(
                        ah[m], bh[n], acc[m][n], 0, 0, 0);
        }
        __syncthreads();
    }

    // epilogue: s = dot_hh * rinv[j]; per-(row, 64-col group) max via u32 atomicMax
    const int colb = col0 + wc * 64;
    const int g    = colb >> 6;           // group id, 0..NG-1
    float ri[4];
    #pragma unroll
    for (int n = 0; n < 4; ++n) {
        int j = colb + n * 16 + fr;
        ri[n] = (j < V) ? rinvP[j] : 0.f;
    }
    #pragma unroll
    for (int m = 0; m < 4; ++m) {
        #pragma unroll
        for (int r = 0; r < 4; ++r) {
            unsigned long long best = 0ULL;
            #pragma unroll
            for (int n = 0; n < 4; ++n) {
                int j = colb + n * 16 + fr;
                if (j < V) {
                    unsigned long long key = pack_key(acc[m][n][r] * ri[n], j);
                    if (key > best) best = key;
                }
            }
            #pragma unroll
            for (int o = 8; o > 0; o >>= 1) {
                unsigned long long other = __shfl_xor(best, o, 64);
                if (other > best) best = other;
            }
            if (fr == 0 && best != 0ULL) {
                int row = row0 + wr * 64 + m * 16 + kg * 4 + r;
                atomicMax(&bmax[(size_t)row * NG + g], (unsigned)(best >> 32));
            }
        }
    }
}

// ---------------- pass 2: flag groups within TAU of row max; exact fp32 refine ----------------
#define TAU 0.008f
#define NGMAX 800

__global__ __launch_bounds__(256) void refine_kernel(
    const float* __restrict__ batch, const float* __restrict__ emb,
    const float* __restrict__ rinvP, const unsigned* __restrict__ bmax,
    int* __restrict__ out, int V, int E, int NG)
{
    const int r   = blockIdx.x;
    const int tid = threadIdx.x;
    __shared__ float arow[512];
    __shared__ float gv[NGMAX];
    __shared__ float part[4][64];
    __shared__ int   lst[NGMAX];
    __shared__ int   cnt;
    __shared__ float wmax[4];

    for (int i = tid; i < E; i += 256) arow[i] = batch[(size_t)r * E + i];
    if (tid == 0) cnt = 0;

    float lm = -3.4e38f;
    for (int g = tid; g < NG; g += 256) {
        unsigned u = bmax[(size_t)r * NG + g];
        unsigned v = (u & 0x80000000u) ? (u & 0x7FFFFFFFu) : ~u;  // un-order
        float f = __uint_as_float(v);
        gv[g] = f;
        lm = fmaxf(lm, f);   // fmaxf drops NaN (never-written groups)
    }
    #pragma unroll
    for (int o = 32; o > 0; o >>= 1) lm = fmaxf(lm, __shfl_xor(lm, o, 64));
    if ((tid & 63) == 0) wmax[tid >> 6] = lm;
    __syncthreads();
    const float m1 = fmaxf(fmaxf(wmax[0], wmax[1]), fmaxf(wmax[2], wmax[3]));
    const float thresh = m1 - TAU;

    for (int g = tid; g < NG; g += 256)
        if (gv[g] >= thresh) { int i = atomicAdd(&cnt, 1); lst[i] = g; }
    __syncthreads();
    const int n = cnt;

    const int colL = tid & 63;
    const int kq   = tid >> 6;    // K quarter 0..3
    unsigned long long best = 0ULL;
    for (int li = 0; li < n; ++li) {
        const int j = lst[li] * 64 + colL;
        float p = 0.f;
        if (j < V) {
            const float4* bp = (const float4*)(emb + (size_t)j * E + kq * 128);
            const float4* ap = (const float4*)(&arow[kq * 128]);
            #pragma unroll 8
            for (int i = 0; i < 32; ++i) {
                float4 b = bp[i], a = ap[i];
                p = fmaf(a.x, b.x, p); p = fmaf(a.y, b.y, p);
                p = fmaf(a.z, b.z, p); p = fmaf(a.w, b.w, p);
            }
        }
        part[kq][colL] = p;
        __syncthreads();
        if (kq == 0 && j < V) {
            float dot = (part[0][colL] + part[1][colL]) +
                        (part[2][colL] + part[3][colL]);   // fixed order: deterministic
            unsigned long long key = pack_key(dot * rinvP[j], j);
            if (key > best) best = key;
        }
        __syncthreads();
    }

    if (tid < 64) {
        #pragma unroll
        for (int o = 32; o > 0; o >>= 1) {
            unsigned long long other = __shfl_xor(best, o, 64);
            if (other > best) best = other;
        }
        if (tid == 0) out[r] = (int)(~(unsigned)(best & 0xFFFFFFFFULL));
    }
}

// ================= fallback fp32 path (round-0, validated) =================
__global__ void init_keys_kernel(unsigned long long* __restrict__ keys, int M) {
    int i = blockIdx.x * blockDim.x + threadIdx.x;
    if (i < M) keys[i] = 0ULL;
}

__global__ void extract_kernel(const unsigned long long* __restrict__ keys,
                               int* __restrict__ out, int M) {
    int i = blockIdx.x * blockDim.x + threadIdx.x;
    if (i < M) out[i] = (int)(~(unsigned)(keys[i] & 0xFFFFFFFFULL));
}

__global__ void inv_norms_kernel(const float* __restrict__ emb,
                                 float* __restrict__ r, int V, int E) {
    int row  = blockIdx.x * (blockDim.x >> 6) + (threadIdx.x >> 6);
    int lane = threadIdx.x & 63;
    if (row >= V) return;
    const float4* p = reinterpret_cast<const float4*>(emb + (size_t)row * E);
    float ss = 0.f;
    int n4 = E >> 2;
    for (int i = lane; i < n4; i += 64) {
        float4 v = p[i];
        ss = fmaf(v.x, v.x, ss); ss = fmaf(v.y, v.y, ss);
        ss = fmaf(v.z, v.z, ss); ss = fmaf(v.w, v.w, ss);
    }
    #pragma unroll
    for (int o = 32; o > 0; o >>= 1) ss += __shfl_down(ss, o, 64);
    if (lane == 0) r[row] = 1.0f / sqrtf(ss);
}

#define FBM 128
#define FBN 128
#define FBK 32
#define LDSPAD 4

__global__ __launch_bounds__(256) void nn_gemm_argmax(
    const float* __restrict__ batch, const float* __restrict__ emb,
    const float* __restrict__ rinv, unsigned long long* __restrict__ keys,
    int M, int V, int E)
{
    __shared__ float As[FBK][FBM + LDSPAD];
    __shared__ float Bs[FBK][FBN + LDSPAD];
    const int tid = threadIdx.x;
    const int tx  = tid & 15;
    const int ty  = tid >> 4;
    const int row0 = blockIdx.y * FBM;
    const int col0 = blockIdx.x * FBN;
    float acc[8][8];
    #pragma unroll
    for (int i = 0; i < 8; ++i)
        #pragma unroll
        for (int j = 0; j < 8; ++j) acc[i][j] = 0.f;
    const int steps = E / FBK;
    for (int ks = 0; ks < steps; ++ks) {
        const int k0 = ks * FBK;
        #pragma unroll
        for (int it = 0; it < 4; ++it) {
            int idx = it * 256 + tid;
            int rr = idx >> 3, cc = idx & 7;
            float4 v = *reinterpret_cast<const float4*>(
                &batch[(size_t)(row0 + rr) * E + k0 + cc * 4]);
            As[cc*4+0][rr] = v.x; As[cc*4+1][rr] = v.y;
            As[cc*4+2][rr] = v.z; As[cc*4+3][rr] = v.w;
        }
        #pragma unroll
        for (int it = 0; it < 4; ++it) {
            int idx = it * 256 + tid;
            int rr = idx >> 3, cc = idx & 7;
            int j = col0 + rr;
            float4 v = make_float4(0.f,0.f,0.f,0.f);
            if (j < V)
                v = *reinterpret_cast<const float4*>(&emb[(size_t)j * E + k0 + cc * 4]);
            Bs[cc*4+0][rr] = v.x; Bs[cc*4+1][rr] = v.y;
            Bs[cc*4+2][rr] = v.z; Bs[cc*4+3][rr] = v.w;
        }
        __syncthreads();
        #pragma unroll
        for (int k = 0; k < FBK; ++k) {
            float4 a0 = *reinterpret_cast<const float4*>(&As[k][ty*8]);
            float4 a1 = *reinterpret_cast<const float4*>(&As[k][ty*8+4]);
            float4 b0 = *reinterpret_cast<const float4*>(&Bs[k][tx*8]);
            float4 b1 = *reinterpret_cast<const float4*>(&Bs[k][tx*8+4]);
            float a[8] = {a0.x,a0.y,a0.z,a0.w,a1.x,a1.y,a1.z,a1.w};
            float b[8] = {b0.x,b0.y,b0.z,b0.w,b1.x,b1.y,b1.z,b1.w};
            #pragma unroll
            for (int i = 0; i < 8; ++i)
                #pragma unroll
                for (int jj = 0; jj < 8; ++jj)
                    acc[i][jj] = fmaf(a[i], b[jj], acc[i][jj]);
        }
        __syncthreads();
    }
    #pragma unroll
    for (int i = 0; i < 8; ++i) {
        const int q = row0 + ty * 8 + i;
        unsigned long long best = 0ULL;
        #pragma unroll
        for (int jj = 0; jj < 8; ++jj) {
            int j = col0 + tx * 8 + jj;
            if (j < V) {
                unsigned long long key = pack_key(acc[i][jj] * rinv[j], j);
                if (key > best) best = key;
            }
        }
        #pragma unroll
        for (int o = 8; o > 0; o >>= 1) {
            unsigned long long other = __shfl_xor(best, o, 64);
            if (other > best) best = other;
        }
        if (tx == 0 && best != 0ULL) atomicMax(&keys[q], best);
    }
}

// ================= launch =================
extern "C" void kernel_launch(void* const* d_in, const int* in_sizes, int n_in,
                              void* d_out, int out_size, void* d_ws, size_t ws_size,
                              hipStream_t stream) {
    const float* batch = (const float*)d_in[0];  // [B,S,E] f32
    const float* emb   = (const float*)d_in[1];  // [V,E]   f32
    int* out = (int*)d_out;

    const int M = out_size;                 // 4096
    const int E = in_sizes[0] / M;          // 512
    const int V = in_sizes[1] / E;          // 50000
    const int NG = (V + 63) / 64;           // 782 groups of 64 cols

    auto al256 = [](size_t x) { return (x + 255) & ~(size_t)255; };
    size_t o_rinv = 0;
    size_t o_keys = al256(o_rinv + (size_t)V * 4);
    size_t o_bmax = al256(o_keys + (size_t)M * 8);
    size_t o_Ah   = al256(o_bmax + (size_t)M * NG * 4);
    size_t o_Bh   = al256(o_Ah  + (size_t)M * E * 2);
    size_t need   = al256(o_Bh  + (size_t)V * E * 2);

    float* rinv = (float*)((char*)d_ws + o_rinv);
    unsigned long long* keys = (unsigned long long*)((char*)d_ws + o_keys);
    unsigned* bmax = (unsigned*)((char*)d_ws + o_bmax);

    if (ws_size >= need && E == 512 && (M % BM) == 0 && NG <= NGMAX) {
        f16* Ah = (f16*)((char*)d_ws + o_Ah);
        f16* Bh = (f16*)((char*)d_ws + o_Bh);

        convert_emb_kernel<<<(V + 3) / 4, 256, 0, stream>>>(emb, Bh, rinv, V, E);
        convert_batch_kernel<<<(M + 3) / 4, 256, 0, stream>>>(batch, Ah, M, E);
        init_bmax_kernel<<<2048, 256, 0, stream>>>(bmax, M * NG);

        dim3 grid(M / BM, (V + BN - 1) / BN);   // 32 x 391
        nn_hh_kernel<<<grid, 256, 0, stream>>>(Ah, Bh, rinv, bmax, M, V, E, NG);

        refine_kernel<<<M, 256, 0, stream>>>(batch, emb, rinv, bmax, out, V, E, NG);
    } else {
        inv_norms_kernel<<<(V + 3) / 4, 256, 0, stream>>>(emb, rinv, V, E);
        init_keys_kernel<<<(M + 255) / 256, 256, 0, stream>>>(keys, M);
        dim3 grid((V + FBN - 1) / FBN, M / FBM);
        nn_gemm_argmax<<<grid, 256, 0, stream>>>(batch, emb, rinv, keys, M, V, E);
        extract_kernel<<<(M + 255) / 256, 256, 0, stream>>>(keys, out, M);
    }
}